// Round 4
// baseline (177.708 us; speedup 1.0000x reference)
//
#include <hip/hip_runtime.h>
#include <cstdint>
#include <cstddef>

#define B_    4
#define C_    64
#define N_    4096   // 64*64
#define FPD_  128
// fold (1/sqrt(64)) * log2(e) into stored Q so attn does pv = exp2(s)
#define QSCALE_ (0.125f * 1.4426950408889634f)

typedef short bf16x8 __attribute__((ext_vector_type(8)));
typedef float f32x4  __attribute__((ext_vector_type(4)));
typedef float f32x16 __attribute__((ext_vector_type(16)));

__device__ inline unsigned short f2bf(float f) {
    union { float f; unsigned int u; } v; v.f = f;
    unsigned int u = v.u;
    return (unsigned short)((u + 0x7FFFu + ((u >> 16) & 1u)) >> 16);  // RNE
}
__device__ inline unsigned int pack2bf(float a, float b) {
    return (unsigned int)f2bf(a) | ((unsigned int)f2bf(b) << 16);
}

union frag_u { bf16x8 v; unsigned int u[4]; };

// ---------------------------------------------------------------- kernel 1
// Fused prep+QKV. Grid 768: pass = bx>>8 (0=Q,1=K,2=V), rem = bx&255 ->
// (b, 64-position tile). Per block: W pass converted to bf16 LDS, x tile
// staged transposed bf16, 8 MFMAs, repack via LDS, coalesced stores.
// Pass 0 also computes fp_proj (in-block) and the sigmoid gate.
__global__ __launch_bounds__(256) void qkv_kernel(
    const float* __restrict__ x,
    const float* __restrict__ Wq, const float* __restrict__ bq,
    const float* __restrict__ Wk, const float* __restrict__ bk,
    const float* __restrict__ Wv, const float* __restrict__ bv,
    const float* __restrict__ fp, const float* __restrict__ Wfp,
    const float* __restrict__ bfp,
    float* __restrict__ gate,
    unsigned short* __restrict__ Qb, unsigned short* __restrict__ Kb,
    unsigned short* __restrict__ Vb)
{
    __shared__ unsigned short xT[64 * 72];   // [p][c] bf16
    __shared__ unsigned short Wl[64 * 72];   // [o][c] bf16
    __shared__ unsigned short rp[64 * 72];   // repack
    __shared__ float gredf[256];
    __shared__ float fpp[64];

    int tid  = threadIdx.x;
    int bx   = blockIdx.x;
    int pass = bx >> 8;
    int rem  = bx & 255;
    int b  = rem >> 6;
    int p0 = (rem & 63) << 6;
    const float* xb = x + (size_t)b * (C_ * N_) + p0;

    const float* Wsrc = (pass == 0) ? Wq : (pass == 1) ? Wk : Wv;
    const float* bsrc = (pass == 0) ? bq : (pass == 1) ? bk : bv;
    float wscale = (pass == 0) ? QSCALE_ : 1.0f;

    // ---- stage W (bf16, vectorized): thread covers 16 consecutive c of one o
    {
        int o  = tid >> 2;
        int cb = (tid & 3) << 4;
        const float4* src = reinterpret_cast<const float4*>(&Wsrc[o * 64 + cb]);
        float4 w0 = src[0], w1 = src[1], w2 = src[2], w3 = src[3];
        uint4 lo, hi;
        lo.x = pack2bf(w0.x * wscale, w0.y * wscale);
        lo.y = pack2bf(w0.z * wscale, w0.w * wscale);
        lo.z = pack2bf(w1.x * wscale, w1.y * wscale);
        lo.w = pack2bf(w1.z * wscale, w1.w * wscale);
        hi.x = pack2bf(w2.x * wscale, w2.y * wscale);
        hi.y = pack2bf(w2.z * wscale, w2.w * wscale);
        hi.z = pack2bf(w3.x * wscale, w3.y * wscale);
        hi.w = pack2bf(w3.z * wscale, w3.w * wscale);
        *reinterpret_cast<uint4*>(&Wl[o * 72 + cb])     = lo;
        *reinterpret_cast<uint4*>(&Wl[o * 72 + cb + 8]) = hi;
    }
    // ---- stage x tile transposed [p][c]
    for (int i = 0; i < 16; ++i) {
        int l = tid + i * 256;
        int c = l >> 6, p = l & 63;
        xT[p * 72 + c] = f2bf(xb[(size_t)c * N_ + p]);
    }
    // ---- fp_proj (pass 0 only): d = tid>>2, quarter k-range per thread
    if (pass == 0) {
        int d = tid >> 2, kq = tid & 3;
        const float4* wrow = reinterpret_cast<const float4*>(&Wfp[d * FPD_ + kq * 32]);
        const float4* frow = reinterpret_cast<const float4*>(&fp[b * FPD_ + kq * 32]);
        float s = 0.f;
        #pragma unroll
        for (int i = 0; i < 8; ++i) {
            float4 w4 = wrow[i], f4 = frow[i];
            s += w4.x * f4.x + w4.y * f4.y + w4.z * f4.z + w4.w * f4.w;
        }
        gredf[tid] = s;
    }
    __syncthreads();
    if (pass == 0 && tid < 64)
        fpp[tid] = bfp[tid] + gredf[tid * 4] + gredf[tid * 4 + 1]
                 + gredf[tid * 4 + 2] + gredf[tid * 4 + 3];
    if (pass == 0) __syncthreads();

    int lane = tid & 63;
    int wv   = __builtin_amdgcn_readfirstlane(tid >> 6);
    int quad = lane >> 4, l16 = lane & 15;
    int prow = wv * 16 + l16;

    bf16x8 bx0 = *reinterpret_cast<bf16x8*>(&xT[prow * 72 + quad * 8]);
    bf16x8 bx1 = *reinterpret_cast<bf16x8*>(&xT[prow * 72 + 32 + quad * 8]);

    float gp = 0.f;
    #pragma unroll
    for (int t4 = 0; t4 < 4; ++t4) {
        bf16x8 a0 = *reinterpret_cast<bf16x8*>(&Wl[(t4 * 16 + l16) * 72 + quad * 8]);
        bf16x8 a1 = *reinterpret_cast<bf16x8*>(&Wl[(t4 * 16 + l16) * 72 + 32 + quad * 8]);
        f32x4 c4 = (f32x4){0.f, 0.f, 0.f, 0.f};
        c4 = __builtin_amdgcn_mfma_f32_16x16x32_bf16(a0, bx0, c4, 0, 0, 0);
        c4 = __builtin_amdgcn_mfma_f32_16x16x32_bf16(a1, bx1, c4, 0, 0, 0);
        float4 bias = *reinterpret_cast<const float4*>(&bsrc[t4 * 16 + quad * 4]);
        c4[0] += bias.x * wscale; c4[1] += bias.y * wscale;
        c4[2] += bias.z * wscale; c4[3] += bias.w * wscale;
        if (pass == 0) {
            gp = fmaf(c4[0], fpp[t4 * 16 + quad * 4 + 0], gp);
            gp = fmaf(c4[1], fpp[t4 * 16 + quad * 4 + 1], gp);
            gp = fmaf(c4[2], fpp[t4 * 16 + quad * 4 + 2], gp);
            gp = fmaf(c4[3], fpp[t4 * 16 + quad * 4 + 3], gp);
        }
        if (pass < 2) {
            int dd = t4 * 16 + quad * 4;
            *reinterpret_cast<ushort2*>(&rp[prow * 72 + dd]) =
                (ushort2){f2bf(c4[0]), f2bf(c4[1])};
            *reinterpret_cast<ushort2*>(&rp[prow * 72 + dd + 2]) =
                (ushort2){f2bf(c4[2]), f2bf(c4[3])};
        } else {
            #pragma unroll
            for (int j = 0; j < 4; ++j)
                rp[(t4 * 16 + quad * 4 + j) * 72 + prow] = f2bf(c4[j]);
        }
    }
    if (pass == 0) {
        gp += __shfl_xor(gp, 16);
        gp += __shfl_xor(gp, 32);
        if (lane < 16) {
            int pos = p0 + wv * 16 + lane;
            float s = gp * (1.0f / QSCALE_);
            gate[b * N_ + pos] = 1.f / (1.f + __expf(-s));
        }
    }
    __syncthreads();

    int row = tid >> 2;
    int cb  = (tid & 3) << 4;
    ushort4 u[4];
    #pragma unroll
    for (int k = 0; k < 4; ++k)
        u[k] = *reinterpret_cast<ushort4*>(&rp[row * 72 + cb + k * 4]);
    unsigned short* dst;
    if (pass == 0)      dst = Qb + ((size_t)b * N_ + p0 + row) * 64 + cb;
    else if (pass == 1) dst = Kb + ((size_t)b * N_ + p0 + row) * 64 + cb;
    else                dst = Vb + ((size_t)b * 64 + row) * N_ + p0 + cb;
    #pragma unroll
    for (int k = 0; k < 4; ++k)
        *reinterpret_cast<ushort4*>(dst + k * 4) = u[k];
}

// ---------------------------------------------------------------- kernel 2
// Flash attention, no-max softmax, K-split x4, 32x32x16 MFMA, S^T trick:
// each wave: 32 q-rows (qh) x 32 k-cols (kh). S^T = K.Q^T -> C/D col = q,
// so P's PV A-frags assemble with 4 half-wave shuffles (no LDS round-trip).
__global__ __launch_bounds__(256, 4) void attn_kernel(
    const unsigned short* __restrict__ Qb, const unsigned short* __restrict__ Kb,
    const unsigned short* __restrict__ Vb, float* __restrict__ Oattn,
    float* __restrict__ lsum)
{
    __shared__ unsigned short Ks[64 * 72];   // [kpos][d]
    __shared__ unsigned short Vs[64 * 72];   // [c][j]

    int tid = threadIdx.x;
    int bx  = blockIdx.x;          // 1024
    int qt  = bx >> 4;
    int grp = bx & 15;
    int b   = grp >> 2;
    int ks  = grp & 3;
    int q0  = qt << 6;
    int kbase = ks << 10;

    int lane = tid & 63;
    int wv   = __builtin_amdgcn_readfirstlane(tid >> 6);
    int qh   = wv & 1;             // q half (32 rows)
    int kh   = wv >> 1;            // k half (32 cols of the 64-tile)
    int h    = lane >> 5;          // half-wave
    int m    = lane & 31;

    // Q B-frags (loop-invariant): B[n=m=q][k=h*8+jj], d chunks of 16
    const unsigned short* Qg =
        Qb + ((size_t)b * N_ + q0 + qh * 32 + m) * 64 + h * 8;
    bf16x8 bq[4];
    #pragma unroll
    for (int c = 0; c < 4; ++c)
        bq[c] = *reinterpret_cast<const bf16x8*>(Qg + c * 16);

    const unsigned short* Kg = Kb + ((size_t)b * N_ + kbase) * 64;
    const unsigned short* Vg = Vb + (size_t)b * 64 * N_ + kbase;

    int srow = tid >> 3;           // 0..31 (+32)
    int scol = (tid & 7) << 3;     // ushort offset, 16B units

    uint4 kr[2], vr[2];
    #pragma unroll
    for (int i = 0; i < 2; ++i) {
        int r = srow + 32 * i;
        kr[i] = *reinterpret_cast<const uint4*>(&Kg[(size_t)r * 64 + scol]);
        vr[i] = *reinterpret_cast<const uint4*>(&Vg[(size_t)r * N_ + scol]);
    }

    f32x16 oacc[2];
    #pragma unroll
    for (int ct = 0; ct < 2; ++ct)
        #pragma unroll
        for (int r = 0; r < 16; ++r) oacc[ct][r] = 0.f;
    float lacc = 0.f;

    const unsigned short* KsA = &Ks[(kh * 32 + m) * 72 + h * 8];
    const unsigned short* Vs0 = &Vs[m * 72 + kh * 32 + h * 8];

    for (int kt = 0; kt < 16; ++kt) {
        __syncthreads();
        #pragma unroll
        for (int i = 0; i < 2; ++i) {
            int r = srow + 32 * i;
            *reinterpret_cast<uint4*>(&Ks[r * 72 + scol]) = kr[i];
            *reinterpret_cast<uint4*>(&Vs[r * 72 + scol]) = vr[i];
        }
        __syncthreads();
        if (kt < 15) {
            int kk = (kt + 1) << 6;
            #pragma unroll
            for (int i = 0; i < 2; ++i) {
                int r = srow + 32 * i;
                kr[i] = *reinterpret_cast<const uint4*>(&Kg[(size_t)(kk + r) * 64 + scol]);
                vr[i] = *reinterpret_cast<const uint4*>(&Vg[(size_t)r * N_ + kk + scol]);
            }
        }

        // S^T = K . Q^T (chained over d)
        f32x16 s;
        #pragma unroll
        for (int r = 0; r < 16; ++r) s[r] = 0.f;
        #pragma unroll
        for (int c = 0; c < 4; ++c) {
            bf16x8 ak = *reinterpret_cast<const bf16x8*>(KsA + c * 16);
            s = __builtin_amdgcn_mfma_f32_32x32x16_bf16(ak, bq[c], s, 0, 0, 0);
        }

        // exp2 + row-sum + bf16 pack
        float p[16]; float rsum = 0.f;
        #pragma unroll
        for (int r = 0; r < 16; ++r) { p[r] = exp2f(s[r]); rsum += p[r]; }
        lacc += rsum + __shfl_xor(rsum, 32);
        unsigned int pk[8];
        #pragma unroll
        for (int i = 0; i < 8; ++i) pk[i] = pack2bf(p[2 * i], p[2 * i + 1]);

        // assemble P A-frags via half-wave exchange (same q on lane^32)
        frag_u ap0, ap1;
        {
            unsigned int s0 = h ? pk[0] : pk[2];
            unsigned int s1 = h ? pk[1] : pk[3];
            unsigned int r0 = __shfl_xor(s0, 32);
            unsigned int r1 = __shfl_xor(s1, 32);
            ap0.u[0] = h ? r0 : pk[0];
            ap0.u[1] = h ? r1 : pk[1];
            ap0.u[2] = h ? pk[2] : r0;
            ap0.u[3] = h ? pk[3] : r1;
            unsigned int s2 = h ? pk[4] : pk[6];
            unsigned int s3 = h ? pk[5] : pk[7];
            unsigned int r2 = __shfl_xor(s2, 32);
            unsigned int r3 = __shfl_xor(s3, 32);
            ap1.u[0] = h ? r2 : pk[4];
            ap1.u[1] = h ? r3 : pk[5];
            ap1.u[2] = h ? pk[6] : r2;
            ap1.u[3] = h ? pk[7] : r3;
        }

        // O += P . V
        #pragma unroll
        for (int ct = 0; ct < 2; ++ct) {
            bf16x8 bv0 = *reinterpret_cast<const bf16x8*>(Vs0 + ct * 32 * 72);
            bf16x8 bv1 = *reinterpret_cast<const bf16x8*>(Vs0 + ct * 32 * 72 + 16);
            oacc[ct] = __builtin_amdgcn_mfma_f32_32x32x16_bf16(ap0.v, bv0, oacc[ct], 0, 0, 0);
            oacc[ct] = __builtin_amdgcn_mfma_f32_32x32x16_bf16(ap1.v, bv1, oacc[ct], 0, 0, 0);
        }
    }

    // accumulate partials: rows q = (r&3)+8*(r>>2)+4h, col = ct*32+m
    float* Og = Oattn + ((size_t)b * N_ + q0 + qh * 32) * 64;
    #pragma unroll
    for (int ct = 0; ct < 2; ++ct)
        #pragma unroll
        for (int r = 0; r < 16; ++r) {
            int ql = (r & 3) + 8 * (r >> 2) + 4 * h;
            unsafeAtomicAdd(&Og[ql * 64 + ct * 32 + m], oacc[ct][r]);
        }
    if (h == 0)
        unsafeAtomicAdd(&lsum[b * N_ + q0 + qh * 32 + m], lacc);
}

// ---------------------------------------------------------------- kernel 3
// MFMA epilogue, split in channel halves (grid 512 = 2 blocks/CU):
// out[half*32.., p] = Wo_half @ t + bo, t = Oattn*(gate/l) + x.
__global__ __launch_bounds__(256) void epi_kernel(
    const float* __restrict__ Oattn, const float* __restrict__ lsum,
    const float* __restrict__ x, const float* __restrict__ gate,
    const float* __restrict__ Wo, const float* __restrict__ bo,
    float* __restrict__ out)
{
    __shared__ float xs[64 * 68];            // [p][c]
    __shared__ unsigned short Wl[32 * 72];   // [o_local][c] bf16
    __shared__ float os[32 * 68];            // [o_local][p]

    int tid  = threadIdx.x;
    int bx   = blockIdx.x;
    int half = bx >> 8;
    int rem  = bx & 255;
    int b  = rem >> 6;
    int p0 = (rem & 63) << 6;
    const float* xb = x + (size_t)b * (C_ * N_) + p0;

    for (int i = 0; i < 16; ++i) {
        int l = tid + i * 256;
        int c = l >> 6, p = l & 63;
        xs[p * 68 + c] = xb[(size_t)c * N_ + p];
    }
    {   // Wo rows half*32..+31 -> bf16 LDS (8 elems/thread)
        int ol = tid >> 3;
        int cb = (tid & 7) << 3;
        const float4* src = reinterpret_cast<const float4*>(
            &Wo[(half * 32 + ol) * 64 + cb]);
        float4 w0 = src[0], w1 = src[1];
        uint2 pkd;
        pkd.x = pack2bf(w0.x, w0.y); pkd.y = pack2bf(w0.z, w0.w);
        *reinterpret_cast<uint2*>(&Wl[ol * 72 + cb]) = pkd;
        pkd.x = pack2bf(w1.x, w1.y); pkd.y = pack2bf(w1.z, w1.w);
        *reinterpret_cast<uint2*>(&Wl[ol * 72 + cb + 4]) = pkd;
    }
    __syncthreads();

    int lane = tid & 63;
    int wv   = __builtin_amdgcn_readfirstlane(tid >> 6);
    int quad = lane >> 4, l16 = lane & 15;
    int prow = wv * 16 + l16;
    int pos  = p0 + prow;

    float gi = gate[b * N_ + pos] / lsum[b * N_ + pos];
    const float* Og = Oattn + ((size_t)b * N_ + pos) * 64;

    bf16x8 bt0, bt1;
    {
        float4 o0 = *reinterpret_cast<const float4*>(&Og[quad * 8]);
        float4 o1 = *reinterpret_cast<const float4*>(&Og[quad * 8 + 4]);
        float4 xa = *reinterpret_cast<float4*>(&xs[prow * 68 + quad * 8]);
        float4 xc = *reinterpret_cast<float4*>(&xs[prow * 68 + quad * 8 + 4]);
        bt0[0] = f2bf(fmaf(o0.x, gi, xa.x)); bt0[1] = f2bf(fmaf(o0.y, gi, xa.y));
        bt0[2] = f2bf(fmaf(o0.z, gi, xa.z)); bt0[3] = f2bf(fmaf(o0.w, gi, xa.w));
        bt0[4] = f2bf(fmaf(o1.x, gi, xc.x)); bt0[5] = f2bf(fmaf(o1.y, gi, xc.y));
        bt0[6] = f2bf(fmaf(o1.z, gi, xc.z)); bt0[7] = f2bf(fmaf(o1.w, gi, xc.w));
        float4 o2 = *reinterpret_cast<const float4*>(&Og[32 + quad * 8]);
        float4 o3 = *reinterpret_cast<const float4*>(&Og[32 + quad * 8 + 4]);
        float4 xe = *reinterpret_cast<float4*>(&xs[prow * 68 + 32 + quad * 8]);
        float4 xg = *reinterpret_cast<float4*>(&xs[prow * 68 + 32 + quad * 8 + 4]);
        bt1[0] = f2bf(fmaf(o2.x, gi, xe.x)); bt1[1] = f2bf(fmaf(o2.y, gi, xe.y));
        bt1[2] = f2bf(fmaf(o2.z, gi, xe.z)); bt1[3] = f2bf(fmaf(o2.w, gi, xe.w));
        bt1[4] = f2bf(fmaf(o3.x, gi, xg.x)); bt1[5] = f2bf(fmaf(o3.y, gi, xg.y));
        bt1[6] = f2bf(fmaf(o3.z, gi, xg.z)); bt1[7] = f2bf(fmaf(o3.w, gi, xg.w));
    }

    #pragma unroll
    for (int tt = 0; tt < 2; ++tt) {
        int ot = half * 2 + tt;
        bf16x8 a0 = *reinterpret_cast<bf16x8*>(&Wl[(tt * 16 + l16) * 72 + quad * 8]);
        bf16x8 a1 = *reinterpret_cast<bf16x8*>(&Wl[(tt * 16 + l16) * 72 + 32 + quad * 8]);
        f32x4 c4 = (f32x4){0.f, 0.f, 0.f, 0.f};
        c4 = __builtin_amdgcn_mfma_f32_16x16x32_bf16(a0, bt0, c4, 0, 0, 0);
        c4 = __builtin_amdgcn_mfma_f32_16x16x32_bf16(a1, bt1, c4, 0, 0, 0);
        float4 bias = *reinterpret_cast<const float4*>(&bo[ot * 16 + quad * 4]);
        c4[0] += bias.x; c4[1] += bias.y; c4[2] += bias.z; c4[3] += bias.w;
        #pragma unroll
        for (int j = 0; j < 4; ++j)
            os[(tt * 16 + quad * 4 + j) * 68 + prow] = c4[j];
    }
    __syncthreads();

    int row = tid >> 3;            // 0..31 local out channel
    int pb  = (tid & 7) << 3;
    float* ob = out + ((size_t)b * 64 + half * 32 + row) * N_ + p0 + pb;
    *reinterpret_cast<float4*>(ob)     = *reinterpret_cast<float4*>(&os[row * 68 + pb]);
    *reinterpret_cast<float4*>(ob + 4) = *reinterpret_cast<float4*>(&os[row * 68 + pb + 4]);
}

// ---------------------------------------------------------------- launch
extern "C" void kernel_launch(void* const* d_in, const int* in_sizes, int n_in,
                              void* d_out, int out_size, void* d_ws, size_t ws_size,
                              hipStream_t stream)
{
    const float* x   = (const float*)d_in[0];
    const float* fp  = (const float*)d_in[1];
    const float* Wq  = (const float*)d_in[2];
    const float* bq  = (const float*)d_in[3];
    const float* Wk  = (const float*)d_in[4];
    const float* bk  = (const float*)d_in[5];
    const float* Wv  = (const float*)d_in[6];
    const float* bv  = (const float*)d_in[7];
    const float* Wo  = (const float*)d_in[8];
    const float* bo  = (const float*)d_in[9];
    const float* Wfp = (const float*)d_in[10];
    const float* bfp = (const float*)d_in[11];
    float* out = (float*)d_out;

    char* ws = (char*)d_ws;
    float* gate = (float*)(ws);                                      // 64 KB
    unsigned short* Qb = (unsigned short*)(ws + 65536);              // 2 MB
    unsigned short* Kb = (unsigned short*)(ws + 65536 + 2097152);    // 2 MB
    unsigned short* Vb = (unsigned short*)(ws + 65536 + 2 * 2097152);// 2 MB
    float* Oattn = (float*)(ws + 65536 + 3 * 2097152);               // 4 MB
    float* lsum  = (float*)(ws + 65536 + 3 * 2097152 + 4194304);     // 64 KB

    hipMemsetAsync(Oattn, 0, 4194304 + 65536, stream);   // O + l accumulators

    hipLaunchKernelGGL(qkv_kernel, dim3(768), dim3(256), 0, stream,
                       x, Wq, bq, Wk, bk, Wv, bv, fp, Wfp, bfp,
                       gate, Qb, Kb, Vb);
    hipLaunchKernelGGL(attn_kernel, dim3(1024), dim3(256), 0, stream,
                       Qb, Kb, Vb, Oattn, lsum);
    hipLaunchKernelGGL(epi_kernel, dim3(512), dim3(256), 0, stream,
                       Oattn, lsum, x, gate, Wo, bo, out);
}

// Round 5
// 166.654 us; speedup vs baseline: 1.0663x; 1.0663x over previous
//
#include <hip/hip_runtime.h>
#include <cstdint>
#include <cstddef>

#define B_    4
#define C_    64
#define N_    4096   // 64*64
#define FPD_  128
// fold (1/sqrt(64)) * log2(e) into stored Q so attn does pv = exp2(s)
#define QSCALE_ (0.125f * 1.4426950408889634f)

typedef short bf16x8 __attribute__((ext_vector_type(8)));
typedef float f32x4  __attribute__((ext_vector_type(4)));
typedef float f32x16 __attribute__((ext_vector_type(16)));

__device__ inline unsigned short f2bf(float f) {
    union { float f; unsigned int u; } v; v.f = f;
    unsigned int u = v.u;
    return (unsigned short)((u + 0x7FFFu + ((u >> 16) & 1u)) >> 16);  // RNE
}
__device__ inline unsigned int pack2bf(float a, float b) {
    return (unsigned int)f2bf(a) | ((unsigned int)f2bf(b) << 16);
}
// hot-loop variant: round-half-up (2 ops per value vs ~5 for RNE);
// differs from RNE only on exact ties -> negligible for P in (0.2, 4.5)
__device__ inline unsigned int pack2bf_fast(float a, float b) {
    union { float f; unsigned int u; } ua, ub; ua.f = a; ub.f = b;
    return ((ua.u + 0x8000u) >> 16) | ((ub.u + 0x8000u) & 0xFFFF0000u);
}

union frag_u { bf16x8 v; unsigned int u[4]; };

// ---------------------------------------------------------------- kernel 1
// Fused prep+QKV. Grid 768: pass = bx>>8 (0=Q,1=K,2=V), rem = bx&255 ->
// (b, 64-position tile). Pass 0 also computes fp_proj in-block and the gate.
__global__ __launch_bounds__(256) void qkv_kernel(
    const float* __restrict__ x,
    const float* __restrict__ Wq, const float* __restrict__ bq,
    const float* __restrict__ Wk, const float* __restrict__ bk,
    const float* __restrict__ Wv, const float* __restrict__ bv,
    const float* __restrict__ fp, const float* __restrict__ Wfp,
    const float* __restrict__ bfp,
    float* __restrict__ gate,
    unsigned short* __restrict__ Qb, unsigned short* __restrict__ Kb,
    unsigned short* __restrict__ Vb)
{
    __shared__ unsigned short xT[64 * 72];   // [p][c] bf16
    __shared__ unsigned short Wl[64 * 72];   // [o][c] bf16
    __shared__ unsigned short rp[64 * 72];   // repack
    __shared__ float gredf[256];
    __shared__ float fpp[64];

    int tid  = threadIdx.x;
    int bx   = blockIdx.x;
    int pass = bx >> 8;
    int rem  = bx & 255;
    int b  = rem >> 6;
    int p0 = (rem & 63) << 6;
    const float* xb = x + (size_t)b * (C_ * N_) + p0;

    const float* Wsrc = (pass == 0) ? Wq : (pass == 1) ? Wk : Wv;
    const float* bsrc = (pass == 0) ? bq : (pass == 1) ? bk : bv;
    float wscale = (pass == 0) ? QSCALE_ : 1.0f;

    {   // stage W bf16
        int o  = tid >> 2;
        int cb = (tid & 3) << 4;
        const float4* src = reinterpret_cast<const float4*>(&Wsrc[o * 64 + cb]);
        float4 w0 = src[0], w1 = src[1], w2 = src[2], w3 = src[3];
        uint4 lo, hi;
        lo.x = pack2bf(w0.x * wscale, w0.y * wscale);
        lo.y = pack2bf(w0.z * wscale, w0.w * wscale);
        lo.z = pack2bf(w1.x * wscale, w1.y * wscale);
        lo.w = pack2bf(w1.z * wscale, w1.w * wscale);
        hi.x = pack2bf(w2.x * wscale, w2.y * wscale);
        hi.y = pack2bf(w2.z * wscale, w2.w * wscale);
        hi.z = pack2bf(w3.x * wscale, w3.y * wscale);
        hi.w = pack2bf(w3.z * wscale, w3.w * wscale);
        *reinterpret_cast<uint4*>(&Wl[o * 72 + cb])     = lo;
        *reinterpret_cast<uint4*>(&Wl[o * 72 + cb + 8]) = hi;
    }
    for (int i = 0; i < 16; ++i) {           // stage x tile transposed [p][c]
        int l = tid + i * 256;
        int c = l >> 6, p = l & 63;
        xT[p * 72 + c] = f2bf(xb[(size_t)c * N_ + p]);
    }
    if (pass == 0) {                         // fp_proj
        int d = tid >> 2, kq = tid & 3;
        const float4* wrow = reinterpret_cast<const float4*>(&Wfp[d * FPD_ + kq * 32]);
        const float4* frow = reinterpret_cast<const float4*>(&fp[b * FPD_ + kq * 32]);
        float s = 0.f;
        #pragma unroll
        for (int i = 0; i < 8; ++i) {
            float4 w4 = wrow[i], f4 = frow[i];
            s += w4.x * f4.x + w4.y * f4.y + w4.z * f4.z + w4.w * f4.w;
        }
        gredf[tid] = s;
    }
    __syncthreads();
    if (pass == 0 && tid < 64)
        fpp[tid] = bfp[tid] + gredf[tid * 4] + gredf[tid * 4 + 1]
                 + gredf[tid * 4 + 2] + gredf[tid * 4 + 3];
    if (pass == 0) __syncthreads();

    int lane = tid & 63;
    int wv   = __builtin_amdgcn_readfirstlane(tid >> 6);
    int quad = lane >> 4, l16 = lane & 15;
    int prow = wv * 16 + l16;

    bf16x8 bx0 = *reinterpret_cast<bf16x8*>(&xT[prow * 72 + quad * 8]);
    bf16x8 bx1 = *reinterpret_cast<bf16x8*>(&xT[prow * 72 + 32 + quad * 8]);

    float gp = 0.f;
    #pragma unroll
    for (int t4 = 0; t4 < 4; ++t4) {
        bf16x8 a0 = *reinterpret_cast<bf16x8*>(&Wl[(t4 * 16 + l16) * 72 + quad * 8]);
        bf16x8 a1 = *reinterpret_cast<bf16x8*>(&Wl[(t4 * 16 + l16) * 72 + 32 + quad * 8]);
        f32x4 c4 = (f32x4){0.f, 0.f, 0.f, 0.f};
        c4 = __builtin_amdgcn_mfma_f32_16x16x32_bf16(a0, bx0, c4, 0, 0, 0);
        c4 = __builtin_amdgcn_mfma_f32_16x16x32_bf16(a1, bx1, c4, 0, 0, 0);
        float4 bias = *reinterpret_cast<const float4*>(&bsrc[t4 * 16 + quad * 4]);
        c4[0] += bias.x * wscale; c4[1] += bias.y * wscale;
        c4[2] += bias.z * wscale; c4[3] += bias.w * wscale;
        if (pass == 0) {
            gp = fmaf(c4[0], fpp[t4 * 16 + quad * 4 + 0], gp);
            gp = fmaf(c4[1], fpp[t4 * 16 + quad * 4 + 1], gp);
            gp = fmaf(c4[2], fpp[t4 * 16 + quad * 4 + 2], gp);
            gp = fmaf(c4[3], fpp[t4 * 16 + quad * 4 + 3], gp);
        }
        if (pass < 2) {
            int dd = t4 * 16 + quad * 4;
            *reinterpret_cast<ushort2*>(&rp[prow * 72 + dd]) =
                (ushort2){f2bf(c4[0]), f2bf(c4[1])};
            *reinterpret_cast<ushort2*>(&rp[prow * 72 + dd + 2]) =
                (ushort2){f2bf(c4[2]), f2bf(c4[3])};
        } else {
            #pragma unroll
            for (int j = 0; j < 4; ++j)
                rp[(t4 * 16 + quad * 4 + j) * 72 + prow] = f2bf(c4[j]);
        }
    }
    if (pass == 0) {
        gp += __shfl_xor(gp, 16);
        gp += __shfl_xor(gp, 32);
        if (lane < 16) {
            int pos = p0 + wv * 16 + lane;
            float s = gp * (1.0f / QSCALE_);
            gate[b * N_ + pos] = 1.f / (1.f + __expf(-s));
        }
    }
    __syncthreads();

    int row = tid >> 2;
    int cb  = (tid & 3) << 4;
    ushort4 u[4];
    #pragma unroll
    for (int k = 0; k < 4; ++k)
        u[k] = *reinterpret_cast<ushort4*>(&rp[row * 72 + cb + k * 4]);
    unsigned short* dst;
    if (pass == 0)      dst = Qb + ((size_t)b * N_ + p0 + row) * 64 + cb;
    else if (pass == 1) dst = Kb + ((size_t)b * N_ + p0 + row) * 64 + cb;
    else                dst = Vb + ((size_t)b * 64 + row) * N_ + p0 + cb;
    #pragma unroll
    for (int k = 0; k < 4; ++k)
        *reinterpret_cast<ushort4*>(dst + k * 4) = u[k];
}

// ---------------------------------------------------------------- kernel 2
// Flash attention, no-max softmax, K-split x4, 32x32x16 MFMA, S^T trick.
// NO ATOMICS: kh=1 waves fold into kh=0 via an LDS overlay at kernel end;
// each ksplit writes a private partial buffer (each address once).
__global__ __launch_bounds__(256, 4) void attn_kernel(
    const unsigned short* __restrict__ Qb, const unsigned short* __restrict__ Kb,
    const unsigned short* __restrict__ Vb, float* __restrict__ Opart,
    float* __restrict__ lpart)
{
    union SmemU {
        struct { unsigned short Ks[64 * 72]; unsigned short Vs[64 * 72]; } kv;
        struct { float o[2][32 * 64]; float l[2][32]; } comb;   // 16.6 KB <= 18 KB
    };
    __shared__ SmemU smem;

    int tid = threadIdx.x;
    int bx  = blockIdx.x;          // 1024
    int qt  = bx >> 4;
    int grp = bx & 15;
    int b   = grp >> 2;
    int ks  = grp & 3;
    int q0  = qt << 6;
    int kbase = ks << 10;

    int lane = tid & 63;
    int wv   = __builtin_amdgcn_readfirstlane(tid >> 6);
    int qh   = wv & 1;             // q half (32 rows)
    int kh   = wv >> 1;            // k half (32 cols of the 64-tile)
    int h    = lane >> 5;          // half-wave
    int m    = lane & 31;

    const unsigned short* Qg =
        Qb + ((size_t)b * N_ + q0 + qh * 32 + m) * 64 + h * 8;
    bf16x8 bq[4];
    #pragma unroll
    for (int c = 0; c < 4; ++c)
        bq[c] = *reinterpret_cast<const bf16x8*>(Qg + c * 16);

    const unsigned short* Kg = Kb + ((size_t)b * N_ + kbase) * 64;
    const unsigned short* Vg = Vb + (size_t)b * 64 * N_ + kbase;

    int srow = tid >> 3;           // 0..31 (+32)
    int scol = (tid & 7) << 3;

    uint4 kr[2], vr[2];
    #pragma unroll
    for (int i = 0; i < 2; ++i) {
        int r = srow + 32 * i;
        kr[i] = *reinterpret_cast<const uint4*>(&Kg[(size_t)r * 64 + scol]);
        vr[i] = *reinterpret_cast<const uint4*>(&Vg[(size_t)r * N_ + scol]);
    }

    f32x16 oacc[2];
    #pragma unroll
    for (int ct = 0; ct < 2; ++ct)
        #pragma unroll
        for (int r = 0; r < 16; ++r) oacc[ct][r] = 0.f;
    float lacc = 0.f;

    const unsigned short* KsA = &smem.kv.Ks[(kh * 32 + m) * 72 + h * 8];
    const unsigned short* Vs0 = &smem.kv.Vs[m * 72 + kh * 32 + h * 8];

    for (int kt = 0; kt < 16; ++kt) {
        __syncthreads();
        #pragma unroll
        for (int i = 0; i < 2; ++i) {
            int r = srow + 32 * i;
            *reinterpret_cast<uint4*>(&smem.kv.Ks[r * 72 + scol]) = kr[i];
            *reinterpret_cast<uint4*>(&smem.kv.Vs[r * 72 + scol]) = vr[i];
        }
        __syncthreads();
        if (kt < 15) {
            int kk = (kt + 1) << 6;
            #pragma unroll
            for (int i = 0; i < 2; ++i) {
                int r = srow + 32 * i;
                kr[i] = *reinterpret_cast<const uint4*>(&Kg[(size_t)(kk + r) * 64 + scol]);
                vr[i] = *reinterpret_cast<const uint4*>(&Vg[(size_t)r * N_ + kk + scol]);
            }
        }

        // S^T = K . Q^T (chained over d)
        f32x16 s;
        #pragma unroll
        for (int r = 0; r < 16; ++r) s[r] = 0.f;
        #pragma unroll
        for (int c = 0; c < 4; ++c) {
            bf16x8 ak = *reinterpret_cast<const bf16x8*>(KsA + c * 16);
            s = __builtin_amdgcn_mfma_f32_32x32x16_bf16(ak, bq[c], s, 0, 0, 0);
        }

        // exp2 + row-sum + bf16 pack (cheap round)
        float p[16]; float rsum = 0.f;
        #pragma unroll
        for (int r = 0; r < 16; ++r) { p[r] = exp2f(s[r]); rsum += p[r]; }
        lacc += rsum + __shfl_xor(rsum, 32);
        unsigned int pk[8];
        #pragma unroll
        for (int i = 0; i < 8; ++i) pk[i] = pack2bf_fast(p[2 * i], p[2 * i + 1]);

        // assemble P A-frags via half-wave exchange
        frag_u ap0, ap1;
        {
            unsigned int s0 = h ? pk[0] : pk[2];
            unsigned int s1 = h ? pk[1] : pk[3];
            unsigned int r0 = __shfl_xor(s0, 32);
            unsigned int r1 = __shfl_xor(s1, 32);
            ap0.u[0] = h ? r0 : pk[0];
            ap0.u[1] = h ? r1 : pk[1];
            ap0.u[2] = h ? pk[2] : r0;
            ap0.u[3] = h ? pk[3] : r1;
            unsigned int s2 = h ? pk[4] : pk[6];
            unsigned int s3 = h ? pk[5] : pk[7];
            unsigned int r2 = __shfl_xor(s2, 32);
            unsigned int r3 = __shfl_xor(s3, 32);
            ap1.u[0] = h ? r2 : pk[4];
            ap1.u[1] = h ? r3 : pk[5];
            ap1.u[2] = h ? pk[6] : r2;
            ap1.u[3] = h ? pk[7] : r3;
        }

        // O += P . V
        #pragma unroll
        for (int ct = 0; ct < 2; ++ct) {
            bf16x8 bv0 = *reinterpret_cast<const bf16x8*>(Vs0 + ct * 32 * 72);
            bf16x8 bv1 = *reinterpret_cast<const bf16x8*>(Vs0 + ct * 32 * 72 + 16);
            oacc[ct] = __builtin_amdgcn_mfma_f32_32x32x16_bf16(ap0.v, bv0, oacc[ct], 0, 0, 0);
            oacc[ct] = __builtin_amdgcn_mfma_f32_32x32x16_bf16(ap1.v, bv1, oacc[ct], 0, 0, 0);
        }
    }

    // ---- combine kh halves in LDS (overlaying Ks/Vs), then plain stores ----
    __syncthreads();                 // all LDS reads of the loop are done
    if (kh == 1) {
        #pragma unroll
        for (int ct = 0; ct < 2; ++ct)
            #pragma unroll
            for (int r = 0; r < 16; ++r) {
                int ql = (r & 3) + 8 * (r >> 2) + 4 * h;
                smem.comb.o[qh][ql * 64 + ct * 32 + m] = oacc[ct][r];
            }
        if (h == 0) smem.comb.l[qh][m] = lacc;
    }
    __syncthreads();
    if (kh == 0) {
        float* Og = Opart + (((size_t)ks * B_ + b) * N_ + q0 + qh * 32) * 64;
        #pragma unroll
        for (int ct = 0; ct < 2; ++ct)
            #pragma unroll
            for (int r = 0; r < 16; ++r) {
                int ql = (r & 3) + 8 * (r >> 2) + 4 * h;
                Og[ql * 64 + ct * 32 + m] =
                    oacc[ct][r] + smem.comb.o[qh][ql * 64 + ct * 32 + m];
            }
        if (h == 0)
            lpart[((size_t)ks * B_ + b) * N_ + q0 + qh * 32 + m] =
                lacc + smem.comb.l[qh][m];
    }
}

// ---------------------------------------------------------------- kernel 3
// MFMA epilogue, channel halves (grid 512): partials summed COALESCED into
// LDS (fixes the old 16B-gather on Oattn), then frags from LDS.
__global__ __launch_bounds__(256) void epi_kernel(
    const float* __restrict__ Opart, const float* __restrict__ lpart,
    const float* __restrict__ x, const float* __restrict__ gate,
    const float* __restrict__ Wo, const float* __restrict__ bo,
    float* __restrict__ out)
{
    __shared__ float xs[64 * 68];            // [p][c]
    __shared__ float osum[64 * 68];          // [p][c] summed partials
    __shared__ unsigned short Wl[32 * 72];   // [o_local][c] bf16
    __shared__ float os[32 * 68];            // out repack [o_local][p]

    int tid  = threadIdx.x;
    int bx   = blockIdx.x;
    int half = bx >> 8;
    int rem  = bx & 255;
    int b  = rem >> 6;
    int p0 = (rem & 63) << 6;
    const float* xb = x + (size_t)b * (C_ * N_) + p0;

    for (int i = 0; i < 16; ++i) {
        int l = tid + i * 256;
        int c = l >> 6, p = l & 63;
        xs[p * 68 + c] = xb[(size_t)c * N_ + p];
    }
    {   // sum 4 ksplit partials, coalesced float4
        const float* Ob = Opart + ((size_t)b * N_ + p0) * 64;
        const size_t kstride = (size_t)B_ * N_ * 64;
        #pragma unroll
        for (int i = 0; i < 4; ++i) {
            int u = tid + i * 256;           // 1024 float4 units
            int p = u >> 4, c4 = (u & 15) << 2;
            size_t off = (size_t)p * 64 + c4;
            float4 a0 = *reinterpret_cast<const float4*>(&Ob[off]);
            float4 a1 = *reinterpret_cast<const float4*>(&Ob[off + kstride]);
            float4 a2 = *reinterpret_cast<const float4*>(&Ob[off + 2 * kstride]);
            float4 a3 = *reinterpret_cast<const float4*>(&Ob[off + 3 * kstride]);
            float4 ssum;
            ssum.x = (a0.x + a1.x) + (a2.x + a3.x);
            ssum.y = (a0.y + a1.y) + (a2.y + a3.y);
            ssum.z = (a0.z + a1.z) + (a2.z + a3.z);
            ssum.w = (a0.w + a1.w) + (a2.w + a3.w);
            *reinterpret_cast<float4*>(&osum[p * 68 + c4]) = ssum;
        }
    }
    {   // Wo rows half*32..+31 -> bf16 LDS
        int ol = tid >> 3;
        int cb = (tid & 7) << 3;
        const float4* src = reinterpret_cast<const float4*>(
            &Wo[(half * 32 + ol) * 64 + cb]);
        float4 w0 = src[0], w1 = src[1];
        uint2 pkd;
        pkd.x = pack2bf(w0.x, w0.y); pkd.y = pack2bf(w0.z, w0.w);
        *reinterpret_cast<uint2*>(&Wl[ol * 72 + cb]) = pkd;
        pkd.x = pack2bf(w1.x, w1.y); pkd.y = pack2bf(w1.z, w1.w);
        *reinterpret_cast<uint2*>(&Wl[ol * 72 + cb + 4]) = pkd;
    }
    __syncthreads();

    int lane = tid & 63;
    int wv   = __builtin_amdgcn_readfirstlane(tid >> 6);
    int quad = lane >> 4, l16 = lane & 15;
    int prow = wv * 16 + l16;
    int pos  = p0 + prow;

    float lv = lpart[(size_t)b * N_ + pos]
             + lpart[((size_t)B_ + b) * N_ + pos]
             + lpart[(2 * (size_t)B_ + b) * N_ + pos]
             + lpart[(3 * (size_t)B_ + b) * N_ + pos];
    float gi = gate[b * N_ + pos] / lv;

    bf16x8 bt[2];
    #pragma unroll
    for (int chunk = 0; chunk < 2; ++chunk) {
        int cb2 = chunk * 32 + quad * 8;
        float4 oa = *reinterpret_cast<float4*>(&osum[prow * 68 + cb2]);
        float4 ob4 = *reinterpret_cast<float4*>(&osum[prow * 68 + cb2 + 4]);
        float4 xa = *reinterpret_cast<float4*>(&xs[prow * 68 + cb2]);
        float4 xb4 = *reinterpret_cast<float4*>(&xs[prow * 68 + cb2 + 4]);
        bt[chunk][0] = f2bf(fmaf(oa.x, gi, xa.x));
        bt[chunk][1] = f2bf(fmaf(oa.y, gi, xa.y));
        bt[chunk][2] = f2bf(fmaf(oa.z, gi, xa.z));
        bt[chunk][3] = f2bf(fmaf(oa.w, gi, xa.w));
        bt[chunk][4] = f2bf(fmaf(ob4.x, gi, xb4.x));
        bt[chunk][5] = f2bf(fmaf(ob4.y, gi, xb4.y));
        bt[chunk][6] = f2bf(fmaf(ob4.z, gi, xb4.z));
        bt[chunk][7] = f2bf(fmaf(ob4.w, gi, xb4.w));
    }

    #pragma unroll
    for (int tt = 0; tt < 2; ++tt) {
        int ot = half * 2 + tt;
        bf16x8 a0 = *reinterpret_cast<bf16x8*>(&Wl[(tt * 16 + l16) * 72 + quad * 8]);
        bf16x8 a1 = *reinterpret_cast<bf16x8*>(&Wl[(tt * 16 + l16) * 72 + 32 + quad * 8]);
        f32x4 c4 = (f32x4){0.f, 0.f, 0.f, 0.f};
        c4 = __builtin_amdgcn_mfma_f32_16x16x32_bf16(a0, bt[0], c4, 0, 0, 0);
        c4 = __builtin_amdgcn_mfma_f32_16x16x32_bf16(a1, bt[1], c4, 0, 0, 0);
        float4 bias = *reinterpret_cast<const float4*>(&bo[ot * 16 + quad * 4]);
        c4[0] += bias.x; c4[1] += bias.y; c4[2] += bias.z; c4[3] += bias.w;
        #pragma unroll
        for (int j = 0; j < 4; ++j)
            os[(tt * 16 + quad * 4 + j) * 68 + prow] = c4[j];
    }
    __syncthreads();

    int row = tid >> 3;
    int pb  = (tid & 7) << 3;
    float* ob = out + ((size_t)b * 64 + half * 32 + row) * N_ + p0 + pb;
    *reinterpret_cast<float4*>(ob)     = *reinterpret_cast<float4*>(&os[row * 68 + pb]);
    *reinterpret_cast<float4*>(ob + 4) = *reinterpret_cast<float4*>(&os[row * 68 + pb + 4]);
}

// ---------------------------------------------------------------- launch
extern "C" void kernel_launch(void* const* d_in, const int* in_sizes, int n_in,
                              void* d_out, int out_size, void* d_ws, size_t ws_size,
                              hipStream_t stream)
{
    const float* x   = (const float*)d_in[0];
    const float* fp  = (const float*)d_in[1];
    const float* Wq  = (const float*)d_in[2];
    const float* bq  = (const float*)d_in[3];
    const float* Wk  = (const float*)d_in[4];
    const float* bk  = (const float*)d_in[5];
    const float* Wv  = (const float*)d_in[6];
    const float* bv  = (const float*)d_in[7];
    const float* Wo  = (const float*)d_in[8];
    const float* bo  = (const float*)d_in[9];
    const float* Wfp = (const float*)d_in[10];
    const float* bfp = (const float*)d_in[11];
    float* out = (float*)d_out;

    char* ws = (char*)d_ws;
    float* gate = (float*)(ws);                                      // 64 KB
    unsigned short* Qb = (unsigned short*)(ws + 65536);              // 2 MB
    unsigned short* Kb = (unsigned short*)(ws + 65536 + 2097152);    // 2 MB
    unsigned short* Vb = (unsigned short*)(ws + 65536 + 2 * 2097152);// 2 MB
    float* Opart = (float*)(ws + 65536 + 3 * 2097152);               // 16 MB (4 x 4 MB)
    float* lpart = (float*)(ws + 65536 + 3 * 2097152 + 16777216);    // 256 KB

    // no memset needed: every Opart/lpart element is written exactly once

    hipLaunchKernelGGL(qkv_kernel, dim3(768), dim3(256), 0, stream,
                       x, Wq, bq, Wk, bk, Wv, bv, fp, Wfp, bfp,
                       gate, Qb, Kb, Vb);
    hipLaunchKernelGGL(attn_kernel, dim3(1024), dim3(256), 0, stream,
                       Qb, Kb, Vb, Opart, lpart);
    hipLaunchKernelGGL(epi_kernel, dim3(512), dim3(256), 0, stream,
                       Opart, lpart, x, gate, Wo, bo, out);
}

// Round 6
// 129.026 us; speedup vs baseline: 1.3773x; 1.2916x over previous
//
#include <hip/hip_runtime.h>
#include <cstdint>
#include <cstddef>

#define B_    4
#define C_    64
#define N_    4096   // 64*64
#define FPD_  128
// fold (1/sqrt(64)) * log2(e) into stored Q so attn does pv = exp2(s)
#define QSCALE_ (0.125f * 1.4426950408889634f)

typedef short bf16x8 __attribute__((ext_vector_type(8)));
typedef float f32x4  __attribute__((ext_vector_type(4)));

__device__ inline unsigned short f2bf(float f) {
    union { float f; unsigned int u; } v; v.f = f;
    unsigned int u = v.u;
    return (unsigned short)((u + 0x7FFFu + ((u >> 16) & 1u)) >> 16);  // RNE
}
__device__ inline unsigned int pack2bf(float a, float b) {
    return (unsigned int)f2bf(a) | ((unsigned int)f2bf(b) << 16);
}
// round-half-up bf16 (2 ops); differs from RNE only on exact ties
__device__ inline unsigned short f2bf_fast(float f) {
    union { float f; unsigned int u; } v; v.f = f;
    return (unsigned short)((v.u + 0x8000u) >> 16);
}

// ---------------------------------------------------------------- kernel 1
// Fused prep+QKV. Grid 768: pass = bx>>8 (0=Q,1=K,2=V), rem = bx&255 ->
// (b, 64-position tile). Pass 0 also computes fp_proj in-block and the gate.
__global__ __launch_bounds__(256) void qkv_kernel(
    const float* __restrict__ x,
    const float* __restrict__ Wq, const float* __restrict__ bq,
    const float* __restrict__ Wk, const float* __restrict__ bk,
    const float* __restrict__ Wv, const float* __restrict__ bv,
    const float* __restrict__ fp, const float* __restrict__ Wfp,
    const float* __restrict__ bfp,
    float* __restrict__ gate,
    unsigned short* __restrict__ Qb, unsigned short* __restrict__ Kb,
    unsigned short* __restrict__ Vb)
{
    __shared__ unsigned short xT[64 * 72];   // [p][c] bf16
    __shared__ unsigned short Wl[64 * 72];   // [o][c] bf16
    __shared__ unsigned short rp[64 * 72];   // repack
    __shared__ float gredf[256];
    __shared__ float fpp[64];

    int tid  = threadIdx.x;
    int bx   = blockIdx.x;
    int pass = bx >> 8;
    int rem  = bx & 255;
    int b  = rem >> 6;
    int p0 = (rem & 63) << 6;
    const float* xb = x + (size_t)b * (C_ * N_) + p0;

    const float* Wsrc = (pass == 0) ? Wq : (pass == 1) ? Wk : Wv;
    const float* bsrc = (pass == 0) ? bq : (pass == 1) ? bk : bv;
    float wscale = (pass == 0) ? QSCALE_ : 1.0f;

    {   // stage W bf16
        int o  = tid >> 2;
        int cb = (tid & 3) << 4;
        const float4* src = reinterpret_cast<const float4*>(&Wsrc[o * 64 + cb]);
        float4 w0 = src[0], w1 = src[1], w2 = src[2], w3 = src[3];
        uint4 lo, hi;
        lo.x = pack2bf(w0.x * wscale, w0.y * wscale);
        lo.y = pack2bf(w0.z * wscale, w0.w * wscale);
        lo.z = pack2bf(w1.x * wscale, w1.y * wscale);
        lo.w = pack2bf(w1.z * wscale, w1.w * wscale);
        hi.x = pack2bf(w2.x * wscale, w2.y * wscale);
        hi.y = pack2bf(w2.z * wscale, w2.w * wscale);
        hi.z = pack2bf(w3.x * wscale, w3.y * wscale);
        hi.w = pack2bf(w3.z * wscale, w3.w * wscale);
        *reinterpret_cast<uint4*>(&Wl[o * 72 + cb])     = lo;
        *reinterpret_cast<uint4*>(&Wl[o * 72 + cb + 8]) = hi;
    }
    for (int i = 0; i < 16; ++i) {           // stage x tile transposed [p][c]
        int l = tid + i * 256;
        int c = l >> 6, p = l & 63;
        xT[p * 72 + c] = f2bf(xb[(size_t)c * N_ + p]);
    }
    if (pass == 0) {                         // fp_proj
        int d = tid >> 2, kq = tid & 3;
        const float4* wrow = reinterpret_cast<const float4*>(&Wfp[d * FPD_ + kq * 32]);
        const float4* frow = reinterpret_cast<const float4*>(&fp[b * FPD_ + kq * 32]);
        float s = 0.f;
        #pragma unroll
        for (int i = 0; i < 8; ++i) {
            float4 w4 = wrow[i], f4 = frow[i];
            s += w4.x * f4.x + w4.y * f4.y + w4.z * f4.z + w4.w * f4.w;
        }
        gredf[tid] = s;
    }
    __syncthreads();
    if (pass == 0 && tid < 64)
        fpp[tid] = bfp[tid] + gredf[tid * 4] + gredf[tid * 4 + 1]
                 + gredf[tid * 4 + 2] + gredf[tid * 4 + 3];
    if (pass == 0) __syncthreads();

    int lane = tid & 63;
    int wv   = __builtin_amdgcn_readfirstlane(tid >> 6);
    int quad = lane >> 4, l16 = lane & 15;
    int prow = wv * 16 + l16;

    bf16x8 bx0 = *reinterpret_cast<bf16x8*>(&xT[prow * 72 + quad * 8]);
    bf16x8 bx1 = *reinterpret_cast<bf16x8*>(&xT[prow * 72 + 32 + quad * 8]);

    float gp = 0.f;
    #pragma unroll
    for (int t4 = 0; t4 < 4; ++t4) {
        bf16x8 a0 = *reinterpret_cast<bf16x8*>(&Wl[(t4 * 16 + l16) * 72 + quad * 8]);
        bf16x8 a1 = *reinterpret_cast<bf16x8*>(&Wl[(t4 * 16 + l16) * 72 + 32 + quad * 8]);
        f32x4 c4 = (f32x4){0.f, 0.f, 0.f, 0.f};
        c4 = __builtin_amdgcn_mfma_f32_16x16x32_bf16(a0, bx0, c4, 0, 0, 0);
        c4 = __builtin_amdgcn_mfma_f32_16x16x32_bf16(a1, bx1, c4, 0, 0, 0);
        float4 bias = *reinterpret_cast<const float4*>(&bsrc[t4 * 16 + quad * 4]);
        c4[0] += bias.x * wscale; c4[1] += bias.y * wscale;
        c4[2] += bias.z * wscale; c4[3] += bias.w * wscale;
        if (pass == 0) {
            gp = fmaf(c4[0], fpp[t4 * 16 + quad * 4 + 0], gp);
            gp = fmaf(c4[1], fpp[t4 * 16 + quad * 4 + 1], gp);
            gp = fmaf(c4[2], fpp[t4 * 16 + quad * 4 + 2], gp);
            gp = fmaf(c4[3], fpp[t4 * 16 + quad * 4 + 3], gp);
        }
        if (pass < 2) {
            int dd = t4 * 16 + quad * 4;
            *reinterpret_cast<ushort2*>(&rp[prow * 72 + dd]) =
                (ushort2){f2bf(c4[0]), f2bf(c4[1])};
            *reinterpret_cast<ushort2*>(&rp[prow * 72 + dd + 2]) =
                (ushort2){f2bf(c4[2]), f2bf(c4[3])};
        } else {
            #pragma unroll
            for (int j = 0; j < 4; ++j)
                rp[(t4 * 16 + quad * 4 + j) * 72 + prow] = f2bf(c4[j]);
        }
    }
    if (pass == 0) {
        gp += __shfl_xor(gp, 16);
        gp += __shfl_xor(gp, 32);
        if (lane < 16) {
            int pos = p0 + wv * 16 + lane;
            float s = gp * (1.0f / QSCALE_);
            gate[b * N_ + pos] = 1.f / (1.f + __expf(-s));
        }
    }
    __syncthreads();

    int row = tid >> 2;
    int cb  = (tid & 3) << 4;
    ushort4 u[4];
    #pragma unroll
    for (int k = 0; k < 4; ++k)
        u[k] = *reinterpret_cast<ushort4*>(&rp[row * 72 + cb + k * 4]);
    unsigned short* dst;
    if (pass == 0)      dst = Qb + ((size_t)b * N_ + p0 + row) * 64 + cb;
    else if (pass == 1) dst = Kb + ((size_t)b * N_ + p0 + row) * 64 + cb;
    else                dst = Vb + ((size_t)b * 64 + row) * N_ + p0 + cb;
    #pragma unroll
    for (int k = 0; k < 4; ++k)
        *reinterpret_cast<ushort4*>(dst + k * 4) = u[k];
}

// ---------------------------------------------------------------- kernel 2
// Flash attention — ROUND-3 CORE (16x16x32 MFMA, P via wave-local LDS strip,
// register K/V prefetch), but NO ATOMICS: each wave owns its 16 q-rows, so
// each ksplit writes a private partial buffer with plain stores (each
// address written exactly once; no memset, no combine step).
__global__ __launch_bounds__(256, 4) void attn_kernel(
    const unsigned short* __restrict__ Qb, const unsigned short* __restrict__ Kb,
    const unsigned short* __restrict__ Vb, float* __restrict__ Opart,
    float* __restrict__ lpart)
{
    __shared__ unsigned short Ks[64 * 72];   // [kj][d]  rows padded to 144 B
    __shared__ unsigned short Vs[64 * 72];   // [c][tj]
    __shared__ unsigned short Ps[64 * 72];   // [qi][tj] per-wave strips

    int tid = threadIdx.x;
    int bx  = blockIdx.x;          // 1024
    int qt  = bx >> 4;             // 0..63
    int grp = bx & 15;
    int b   = grp >> 2;
    int ks  = grp & 3;
    int q0  = qt << 6;
    int kbase = ks << 10;          // 1024-column K window

    int lane = tid & 63;
    int wv   = __builtin_amdgcn_readfirstlane(tid >> 6);
    int quad = lane >> 4, l16 = lane & 15;
    int qs0  = wv << 4;

    // Q A-frags straight from global (16B aligned): A[m=l16][k=quad*8+j]
    const unsigned short* Qg = Qb + ((size_t)b * N_ + q0) * 64;
    bf16x8 aq0 = *reinterpret_cast<const bf16x8*>(&Qg[(qs0 + l16) * 64 + quad * 8]);
    bf16x8 aq1 = *reinterpret_cast<const bf16x8*>(&Qg[(qs0 + l16) * 64 + 32 + quad * 8]);

    const unsigned short* Kg = Kb + ((size_t)b * N_ + kbase) * 64;
    const unsigned short* Vg = Vb + (size_t)b * 64 * N_ + kbase;

    int r0 = tid >> 4;             // staging row 0..15 (+16*i)
    int cc = (tid & 15) << 2;      // staging col (ushort4 units)

    ushort4 kr[4], vr[4];
    #pragma unroll
    for (int i = 0; i < 4; ++i) {
        int r = r0 + 16 * i;
        kr[i] = *reinterpret_cast<const ushort4*>(&Kg[(size_t)r * 64 + cc]);
        vr[i] = *reinterpret_cast<const ushort4*>(&Vg[(size_t)r * N_ + cc]);
    }

    f32x4 oacc[4]; f32x4 lacc = (f32x4){0.f, 0.f, 0.f, 0.f};
    #pragma unroll
    for (int cs = 0; cs < 4; ++cs) oacc[cs] = (f32x4){0.f, 0.f, 0.f, 0.f};
    bf16x8 ones;
    #pragma unroll
    for (int i = 0; i < 8; ++i) ones[i] = (short)0x3F80;   // bf16 1.0

    for (int kt = 0; kt < 16; ++kt) {
        __syncthreads();                     // prev-iter frag reads done
        #pragma unroll
        for (int i = 0; i < 4; ++i) {
            int r = r0 + 16 * i;
            *reinterpret_cast<ushort4*>(&Ks[r * 72 + cc]) = kr[i];
            *reinterpret_cast<ushort4*>(&Vs[r * 72 + cc]) = vr[i];
        }
        __syncthreads();
        if (kt < 15) {                       // prefetch next tile
            int kk = (kt + 1) << 6;
            #pragma unroll
            for (int i = 0; i < 4; ++i) {
                int r = r0 + 16 * i;
                kr[i] = *reinterpret_cast<const ushort4*>(&Kg[(size_t)(kk + r) * 64 + cc]);
                vr[i] = *reinterpret_cast<const ushort4*>(&Vg[(size_t)r * N_ + kk + cc]);
            }
        }

        // S = Q K^T (scale pre-folded), P = exp2(S) -> LDS (C/D -> A transform)
        #pragma unroll
        for (int kj = 0; kj < 4; ++kj) {
            bf16x8 bk0 = *reinterpret_cast<bf16x8*>(&Ks[(kj * 16 + l16) * 72 + quad * 8]);
            bf16x8 bk1 = *reinterpret_cast<bf16x8*>(&Ks[(kj * 16 + l16) * 72 + 32 + quad * 8]);
            f32x4 s = (f32x4){0.f, 0.f, 0.f, 0.f};
            s = __builtin_amdgcn_mfma_f32_16x16x32_bf16(aq0, bk0, s, 0, 0, 0);
            s = __builtin_amdgcn_mfma_f32_16x16x32_bf16(aq1, bk1, s, 0, 0, 0);
            #pragma unroll
            for (int j = 0; j < 4; ++j) {
                float pv = exp2f(s[j]);      // v_exp_f32
                Ps[(qs0 + quad * 4 + j) * 72 + kj * 16 + l16] = f2bf_fast(pv);
            }
        }
        __asm__ volatile("s_waitcnt lgkmcnt(0)" ::: "memory");  // wave-local strip

        bf16x8 ap0 = *reinterpret_cast<bf16x8*>(&Ps[(qs0 + l16) * 72 + quad * 8]);
        bf16x8 ap1 = *reinterpret_cast<bf16x8*>(&Ps[(qs0 + l16) * 72 + 32 + quad * 8]);
        lacc = __builtin_amdgcn_mfma_f32_16x16x32_bf16(ap0, ones, lacc, 0, 0, 0);
        lacc = __builtin_amdgcn_mfma_f32_16x16x32_bf16(ap1, ones, lacc, 0, 0, 0);
        #pragma unroll
        for (int cs = 0; cs < 4; ++cs) {
            bf16x8 bv0 = *reinterpret_cast<bf16x8*>(&Vs[(cs * 16 + l16) * 72 + quad * 8]);
            bf16x8 bv1 = *reinterpret_cast<bf16x8*>(&Vs[(cs * 16 + l16) * 72 + 32 + quad * 8]);
            oacc[cs] = __builtin_amdgcn_mfma_f32_16x16x32_bf16(ap0, bv0, oacc[cs], 0, 0, 0);
            oacc[cs] = __builtin_amdgcn_mfma_f32_16x16x32_bf16(ap1, bv1, oacc[cs], 0, 0, 0);
        }
    }

    // private-partial stores: each address written exactly once grid-wide
    float* Og = Opart + (((size_t)ks * B_ + b) * N_ + q0) * 64;
    #pragma unroll
    for (int j = 0; j < 4; ++j) {
        int row = qs0 + quad * 4 + j;
        #pragma unroll
        for (int cs = 0; cs < 4; ++cs)
            Og[row * 64 + cs * 16 + l16] = oacc[cs][j];
    }
    if (l16 == 0) {
        #pragma unroll
        for (int j = 0; j < 4; ++j)
            lpart[((size_t)ks * B_ + b) * N_ + q0 + qs0 + quad * 4 + j] = lacc[j];
    }
}

// ---------------------------------------------------------------- kernel 3
// MFMA epilogue, channel halves (grid 512): partials summed COALESCED into
// LDS, then frags from LDS.
__global__ __launch_bounds__(256) void epi_kernel(
    const float* __restrict__ Opart, const float* __restrict__ lpart,
    const float* __restrict__ x, const float* __restrict__ gate,
    const float* __restrict__ Wo, const float* __restrict__ bo,
    float* __restrict__ out)
{
    __shared__ float xs[64 * 68];            // [p][c]
    __shared__ float osum[64 * 68];          // [p][c] summed partials
    __shared__ unsigned short Wl[32 * 72];   // [o_local][c] bf16
    __shared__ float os[32 * 68];            // out repack [o_local][p]

    int tid  = threadIdx.x;
    int bx   = blockIdx.x;
    int half = bx >> 8;
    int rem  = bx & 255;
    int b  = rem >> 6;
    int p0 = (rem & 63) << 6;
    const float* xb = x + (size_t)b * (C_ * N_) + p0;

    for (int i = 0; i < 16; ++i) {
        int l = tid + i * 256;
        int c = l >> 6, p = l & 63;
        xs[p * 68 + c] = xb[(size_t)c * N_ + p];
    }
    {   // sum 4 ksplit partials, coalesced float4
        const float* Ob = Opart + ((size_t)b * N_ + p0) * 64;
        const size_t kstride = (size_t)B_ * N_ * 64;
        #pragma unroll
        for (int i = 0; i < 4; ++i) {
            int u = tid + i * 256;           // 1024 float4 units
            int p = u >> 4, c4 = (u & 15) << 2;
            size_t off = (size_t)p * 64 + c4;
            float4 a0 = *reinterpret_cast<const float4*>(&Ob[off]);
            float4 a1 = *reinterpret_cast<const float4*>(&Ob[off + kstride]);
            float4 a2 = *reinterpret_cast<const float4*>(&Ob[off + 2 * kstride]);
            float4 a3 = *reinterpret_cast<const float4*>(&Ob[off + 3 * kstride]);
            float4 ssum;
            ssum.x = (a0.x + a1.x) + (a2.x + a3.x);
            ssum.y = (a0.y + a1.y) + (a2.y + a3.y);
            ssum.z = (a0.z + a1.z) + (a2.z + a3.z);
            ssum.w = (a0.w + a1.w) + (a2.w + a3.w);
            *reinterpret_cast<float4*>(&osum[p * 68 + c4]) = ssum;
        }
    }
    {   // Wo rows half*32..+31 -> bf16 LDS
        int ol = tid >> 3;
        int cb = (tid & 7) << 3;
        const float4* src = reinterpret_cast<const float4*>(
            &Wo[(half * 32 + ol) * 64 + cb]);
        float4 w0 = src[0], w1 = src[1];
        uint2 pkd;
        pkd.x = pack2bf(w0.x, w0.y); pkd.y = pack2bf(w0.z, w0.w);
        *reinterpret_cast<uint2*>(&Wl[ol * 72 + cb]) = pkd;
        pkd.x = pack2bf(w1.x, w1.y); pkd.y = pack2bf(w1.z, w1.w);
        *reinterpret_cast<uint2*>(&Wl[ol * 72 + cb + 4]) = pkd;
    }
    __syncthreads();

    int lane = tid & 63;
    int wv   = __builtin_amdgcn_readfirstlane(tid >> 6);
    int quad = lane >> 4, l16 = lane & 15;
    int prow = wv * 16 + l16;
    int pos  = p0 + prow;

    float lv = lpart[(size_t)b * N_ + pos]
             + lpart[((size_t)B_ + b) * N_ + pos]
             + lpart[(2 * (size_t)B_ + b) * N_ + pos]
             + lpart[(3 * (size_t)B_ + b) * N_ + pos];
    float gi = gate[b * N_ + pos] / lv;

    bf16x8 bt[2];
    #pragma unroll
    for (int chunk = 0; chunk < 2; ++chunk) {
        int cb2 = chunk * 32 + quad * 8;
        float4 oa = *reinterpret_cast<float4*>(&osum[prow * 68 + cb2]);
        float4 ob4 = *reinterpret_cast<float4*>(&osum[prow * 68 + cb2 + 4]);
        float4 xa = *reinterpret_cast<float4*>(&xs[prow * 68 + cb2]);
        float4 xb4 = *reinterpret_cast<float4*>(&xs[prow * 68 + cb2 + 4]);
        bt[chunk][0] = f2bf(fmaf(oa.x, gi, xa.x));
        bt[chunk][1] = f2bf(fmaf(oa.y, gi, xa.y));
        bt[chunk][2] = f2bf(fmaf(oa.z, gi, xa.z));
        bt[chunk][3] = f2bf(fmaf(oa.w, gi, xa.w));
        bt[chunk][4] = f2bf(fmaf(ob4.x, gi, xb4.x));
        bt[chunk][5] = f2bf(fmaf(ob4.y, gi, xb4.y));
        bt[chunk][6] = f2bf(fmaf(ob4.z, gi, xb4.z));
        bt[chunk][7] = f2bf(fmaf(ob4.w, gi, xb4.w));
    }

    #pragma unroll
    for (int tt = 0; tt < 2; ++tt) {
        int ot = half * 2 + tt;
        bf16x8 a0 = *reinterpret_cast<bf16x8*>(&Wl[(tt * 16 + l16) * 72 + quad * 8]);
        bf16x8 a1 = *reinterpret_cast<bf16x8*>(&Wl[(tt * 16 + l16) * 72 + 32 + quad * 8]);
        f32x4 c4 = (f32x4){0.f, 0.f, 0.f, 0.f};
        c4 = __builtin_amdgcn_mfma_f32_16x16x32_bf16(a0, bt[0], c4, 0, 0, 0);
        c4 = __builtin_amdgcn_mfma_f32_16x16x32_bf16(a1, bt[1], c4, 0, 0, 0);
        float4 bias = *reinterpret_cast<const float4*>(&bo[ot * 16 + quad * 4]);
        c4[0] += bias.x; c4[1] += bias.y; c4[2] += bias.z; c4[3] += bias.w;
        #pragma unroll
        for (int j = 0; j < 4; ++j)
            os[(tt * 16 + quad * 4 + j) * 68 + prow] = c4[j];
    }
    __syncthreads();

    int row = tid >> 3;
    int pb  = (tid & 7) << 3;
    float* ob = out + ((size_t)b * 64 + half * 32 + row) * N_ + p0 + pb;
    *reinterpret_cast<float4*>(ob)     = *reinterpret_cast<float4*>(&os[row * 68 + pb]);
    *reinterpret_cast<float4*>(ob + 4) = *reinterpret_cast<float4*>(&os[row * 68 + pb + 4]);
}

// ---------------------------------------------------------------- launch
extern "C" void kernel_launch(void* const* d_in, const int* in_sizes, int n_in,
                              void* d_out, int out_size, void* d_ws, size_t ws_size,
                              hipStream_t stream)
{
    const float* x   = (const float*)d_in[0];
    const float* fp  = (const float*)d_in[1];
    const float* Wq  = (const float*)d_in[2];
    const float* bq  = (const float*)d_in[3];
    const float* Wk  = (const float*)d_in[4];
    const float* bk  = (const float*)d_in[5];
    const float* Wv  = (const float*)d_in[6];
    const float* bv  = (const float*)d_in[7];
    const float* Wo  = (const float*)d_in[8];
    const float* bo  = (const float*)d_in[9];
    const float* Wfp = (const float*)d_in[10];
    const float* bfp = (const float*)d_in[11];
    float* out = (float*)d_out;

    char* ws = (char*)d_ws;
    float* gate = (float*)(ws);                                      // 64 KB
    unsigned short* Qb = (unsigned short*)(ws + 65536);              // 2 MB
    unsigned short* Kb = (unsigned short*)(ws + 65536 + 2097152);    // 2 MB
    unsigned short* Vb = (unsigned short*)(ws + 65536 + 2 * 2097152);// 2 MB
    float* Opart = (float*)(ws + 65536 + 3 * 2097152);               // 16 MB (4 x 4 MB)
    float* lpart = (float*)(ws + 65536 + 3 * 2097152 + 16777216);    // 256 KB

    // no memset needed: every Opart/lpart element is written exactly once

    hipLaunchKernelGGL(qkv_kernel, dim3(768), dim3(256), 0, stream,
                       x, Wq, bq, Wk, bk, Wv, bv, fp, Wfp, bfp,
                       gate, Qb, Kb, Vb);
    hipLaunchKernelGGL(attn_kernel, dim3(1024), dim3(256), 0, stream,
                       Qb, Kb, Vb, Opart, lpart);
    hipLaunchKernelGGL(epi_kernel, dim3(512), dim3(256), 0, stream,
                       Opart, lpart, x, gate, Wo, bo, out);
}

// Round 7
// 118.647 us; speedup vs baseline: 1.4978x; 1.0875x over previous
//
#include <hip/hip_runtime.h>
#include <cstdint>
#include <cstddef>

#define B_    4
#define C_    64
#define N_    4096   // 64*64
#define FPD_  128
// fold (1/sqrt(64)) * log2(e) into stored Q so attn does pv = exp2(s)
#define QSCALE_ (0.125f * 1.4426950408889634f)

#if __has_builtin(__builtin_amdgcn_exp2f)
#define EXP2(x) __builtin_amdgcn_exp2f(x)
#else
#define EXP2(x) exp2f(x)
#endif

typedef short bf16x8 __attribute__((ext_vector_type(8)));
typedef float f32x4  __attribute__((ext_vector_type(4)));

__device__ inline unsigned short f2bf(float f) {
    union { float f; unsigned int u; } v; v.f = f;
    unsigned int u = v.u;
    return (unsigned short)((u + 0x7FFFu + ((u >> 16) & 1u)) >> 16);  // RNE
}
__device__ inline unsigned int pack2bf(float a, float b) {
    return (unsigned int)f2bf(a) | ((unsigned int)f2bf(b) << 16);
}
// round-half-up bf16 (2 ops); differs from RNE only on exact ties
__device__ inline unsigned short f2bf_fast(float f) {
    union { float f; unsigned int u; } v; v.f = f;
    return (unsigned short)((v.u + 0x8000u) >> 16);
}
__device__ inline float bflo(unsigned int u) {
    union { unsigned int u; float f; } v; v.u = u << 16; return v.f;
}
__device__ inline float bfhi(unsigned int u) {
    union { unsigned int u; float f; } v; v.u = u & 0xFFFF0000u; return v.f;
}

// ---------------------------------------------------------------- kernel 1
// Fused prep+QKV. Grid 768: pass = bx>>8 (0=Q,1=K,2=V), rem = bx&255 ->
// (b, 64-position tile). Pass 0 also computes fp_proj in-block and the gate.
__global__ __launch_bounds__(256) void qkv_kernel(
    const float* __restrict__ x,
    const float* __restrict__ Wq, const float* __restrict__ bq,
    const float* __restrict__ Wk, const float* __restrict__ bk,
    const float* __restrict__ Wv, const float* __restrict__ bv,
    const float* __restrict__ fp, const float* __restrict__ Wfp,
    const float* __restrict__ bfp,
    float* __restrict__ gate,
    unsigned short* __restrict__ Qb, unsigned short* __restrict__ Kb,
    unsigned short* __restrict__ Vb)
{
    __shared__ unsigned short xT[64 * 72];   // [p][c] bf16
    __shared__ unsigned short Wl[64 * 72];   // [o][c] bf16
    __shared__ unsigned short rp[64 * 72];   // repack
    __shared__ float gredf[256];
    __shared__ float fpp[64];

    int tid  = threadIdx.x;
    int bx   = blockIdx.x;
    int pass = bx >> 8;
    int rem  = bx & 255;
    int b  = rem >> 6;
    int p0 = (rem & 63) << 6;
    const float* xb = x + (size_t)b * (C_ * N_) + p0;

    const float* Wsrc = (pass == 0) ? Wq : (pass == 1) ? Wk : Wv;
    const float* bsrc = (pass == 0) ? bq : (pass == 1) ? bk : bv;
    float wscale = (pass == 0) ? QSCALE_ : 1.0f;

    {   // stage W bf16
        int o  = tid >> 2;
        int cb = (tid & 3) << 4;
        const float4* src = reinterpret_cast<const float4*>(&Wsrc[o * 64 + cb]);
        float4 w0 = src[0], w1 = src[1], w2 = src[2], w3 = src[3];
        uint4 lo, hi;
        lo.x = pack2bf(w0.x * wscale, w0.y * wscale);
        lo.y = pack2bf(w0.z * wscale, w0.w * wscale);
        lo.z = pack2bf(w1.x * wscale, w1.y * wscale);
        lo.w = pack2bf(w1.z * wscale, w1.w * wscale);
        hi.x = pack2bf(w2.x * wscale, w2.y * wscale);
        hi.y = pack2bf(w2.z * wscale, w2.w * wscale);
        hi.z = pack2bf(w3.x * wscale, w3.y * wscale);
        hi.w = pack2bf(w3.z * wscale, w3.w * wscale);
        *reinterpret_cast<uint4*>(&Wl[o * 72 + cb])     = lo;
        *reinterpret_cast<uint4*>(&Wl[o * 72 + cb + 8]) = hi;
    }
    // stage x tile transposed [p][c] bf16 — float4 loads (4 p of one c)
    #pragma unroll
    for (int i = 0; i < 4; ++i) {
        int u = tid + i * 256;               // 1024 units
        int c = u >> 4, p4 = (u & 15) << 2;
        float4 v = *reinterpret_cast<const float4*>(&xb[(size_t)c * N_ + p4]);
        xT[(p4 + 0) * 72 + c] = f2bf(v.x);
        xT[(p4 + 1) * 72 + c] = f2bf(v.y);
        xT[(p4 + 2) * 72 + c] = f2bf(v.z);
        xT[(p4 + 3) * 72 + c] = f2bf(v.w);
    }
    if (pass == 0) {                         // fp_proj
        int d = tid >> 2, kq = tid & 3;
        const float4* wrow = reinterpret_cast<const float4*>(&Wfp[d * FPD_ + kq * 32]);
        const float4* frow = reinterpret_cast<const float4*>(&fp[b * FPD_ + kq * 32]);
        float s = 0.f;
        #pragma unroll
        for (int i = 0; i < 8; ++i) {
            float4 w4 = wrow[i], f4 = frow[i];
            s += w4.x * f4.x + w4.y * f4.y + w4.z * f4.z + w4.w * f4.w;
        }
        gredf[tid] = s;
    }
    __syncthreads();
    if (pass == 0 && tid < 64)
        fpp[tid] = bfp[tid] + gredf[tid * 4] + gredf[tid * 4 + 1]
                 + gredf[tid * 4 + 2] + gredf[tid * 4 + 3];
    if (pass == 0) __syncthreads();

    int lane = tid & 63;
    int wv   = __builtin_amdgcn_readfirstlane(tid >> 6);
    int quad = lane >> 4, l16 = lane & 15;
    int prow = wv * 16 + l16;

    bf16x8 bx0 = *reinterpret_cast<bf16x8*>(&xT[prow * 72 + quad * 8]);
    bf16x8 bx1 = *reinterpret_cast<bf16x8*>(&xT[prow * 72 + 32 + quad * 8]);

    float gp = 0.f;
    #pragma unroll
    for (int t4 = 0; t4 < 4; ++t4) {
        bf16x8 a0 = *reinterpret_cast<bf16x8*>(&Wl[(t4 * 16 + l16) * 72 + quad * 8]);
        bf16x8 a1 = *reinterpret_cast<bf16x8*>(&Wl[(t4 * 16 + l16) * 72 + 32 + quad * 8]);
        f32x4 c4 = (f32x4){0.f, 0.f, 0.f, 0.f};
        c4 = __builtin_amdgcn_mfma_f32_16x16x32_bf16(a0, bx0, c4, 0, 0, 0);
        c4 = __builtin_amdgcn_mfma_f32_16x16x32_bf16(a1, bx1, c4, 0, 0, 0);
        float4 bias = *reinterpret_cast<const float4*>(&bsrc[t4 * 16 + quad * 4]);
        c4[0] += bias.x * wscale; c4[1] += bias.y * wscale;
        c4[2] += bias.z * wscale; c4[3] += bias.w * wscale;
        if (pass == 0) {
            gp = fmaf(c4[0], fpp[t4 * 16 + quad * 4 + 0], gp);
            gp = fmaf(c4[1], fpp[t4 * 16 + quad * 4 + 1], gp);
            gp = fmaf(c4[2], fpp[t4 * 16 + quad * 4 + 2], gp);
            gp = fmaf(c4[3], fpp[t4 * 16 + quad * 4 + 3], gp);
        }
        if (pass < 2) {
            int dd = t4 * 16 + quad * 4;
            *reinterpret_cast<ushort2*>(&rp[prow * 72 + dd]) =
                (ushort2){f2bf(c4[0]), f2bf(c4[1])};
            *reinterpret_cast<ushort2*>(&rp[prow * 72 + dd + 2]) =
                (ushort2){f2bf(c4[2]), f2bf(c4[3])};
        } else {
            #pragma unroll
            for (int j = 0; j < 4; ++j)
                rp[(t4 * 16 + quad * 4 + j) * 72 + prow] = f2bf(c4[j]);
        }
    }
    if (pass == 0) {
        gp += __shfl_xor(gp, 16);
        gp += __shfl_xor(gp, 32);
        if (lane < 16) {
            int pos = p0 + wv * 16 + lane;
            float s = gp * (1.0f / QSCALE_);
            gate[b * N_ + pos] = 1.f / (1.f + __expf(-s));
        }
    }
    __syncthreads();

    int row = tid >> 2;
    int cb  = (tid & 3) << 4;
    ushort4 u[4];
    #pragma unroll
    for (int k = 0; k < 4; ++k)
        u[k] = *reinterpret_cast<ushort4*>(&rp[row * 72 + cb + k * 4]);
    unsigned short* dst;
    if (pass == 0)      dst = Qb + ((size_t)b * N_ + p0 + row) * 64 + cb;
    else if (pass == 1) dst = Kb + ((size_t)b * N_ + p0 + row) * 64 + cb;
    else                dst = Vb + ((size_t)b * 64 + row) * N_ + p0 + cb;
    #pragma unroll
    for (int k = 0; k < 4; ++k)
        *reinterpret_cast<ushort4*>(dst + k * 4) = u[k];
}

// ---------------------------------------------------------------- kernel 2
// Flash attention, 16x16x32 core, 32 q-rows per wave (128 q/block):
// K/V fragment reads shared across both q-strips -> 1.6x less LDS traffic.
// Grid 512 = 4b x 32 qtiles x 4 ksplit. Private bf16 partials, no atomics.
__global__ __launch_bounds__(256, 2) void attn_kernel(
    const unsigned short* __restrict__ Qb, const unsigned short* __restrict__ Kb,
    const unsigned short* __restrict__ Vb, unsigned short* __restrict__ Opart,
    float* __restrict__ lpart)
{
    __shared__ unsigned short Ks[64 * 72];    // [kj][d]
    __shared__ unsigned short Vs[64 * 72];    // [c][tj]
    __shared__ unsigned short Ps[128 * 72];   // [qi][tj] per-wave 32-row strips

    int tid = threadIdx.x;
    int bx  = blockIdx.x;          // 512
    int qt  = bx >> 4;             // 0..31
    int grp = bx & 15;
    int b   = grp >> 2;
    int ks  = grp & 3;
    int q0  = qt << 7;             // 128-row q tile
    int kbase = ks << 10;          // 1024-column K window

    int lane = tid & 63;
    int wv   = __builtin_amdgcn_readfirstlane(tid >> 6);
    int quad = lane >> 4, l16 = lane & 15;
    int qs0  = wv << 5;            // wave's 32-row strip base

    // Q A-frags for both 16-row strips (loop-invariant)
    const unsigned short* Qg = Qb + ((size_t)b * N_ + q0) * 64;
    bf16x8 aq[2][2];
    #pragma unroll
    for (int s = 0; s < 2; ++s) {
        aq[s][0] = *reinterpret_cast<const bf16x8*>(
            &Qg[(qs0 + s * 16 + l16) * 64 + quad * 8]);
        aq[s][1] = *reinterpret_cast<const bf16x8*>(
            &Qg[(qs0 + s * 16 + l16) * 64 + 32 + quad * 8]);
    }

    const unsigned short* Kg = Kb + ((size_t)b * N_ + kbase) * 64;
    const unsigned short* Vg = Vb + (size_t)b * 64 * N_ + kbase;

    int r0 = tid >> 4;             // staging row 0..15 (+16*i)
    int cc = (tid & 15) << 2;      // staging col (ushort4 units)

    ushort4 kr[4], vr[4];
    #pragma unroll
    for (int i = 0; i < 4; ++i) {
        int r = r0 + 16 * i;
        kr[i] = *reinterpret_cast<const ushort4*>(&Kg[(size_t)r * 64 + cc]);
        vr[i] = *reinterpret_cast<const ushort4*>(&Vg[(size_t)r * N_ + cc]);
    }

    f32x4 oacc[2][4]; f32x4 lacc[2];
    #pragma unroll
    for (int s = 0; s < 2; ++s) {
        lacc[s] = (f32x4){0.f, 0.f, 0.f, 0.f};
        #pragma unroll
        for (int cs = 0; cs < 4; ++cs) oacc[s][cs] = (f32x4){0.f, 0.f, 0.f, 0.f};
    }
    bf16x8 ones;
    #pragma unroll
    for (int i = 0; i < 8; ++i) ones[i] = (short)0x3F80;   // bf16 1.0

    for (int kt = 0; kt < 16; ++kt) {
        __syncthreads();                     // prev-iter frag reads done
        #pragma unroll
        for (int i = 0; i < 4; ++i) {
            int r = r0 + 16 * i;
            *reinterpret_cast<ushort4*>(&Ks[r * 72 + cc]) = kr[i];
            *reinterpret_cast<ushort4*>(&Vs[r * 72 + cc]) = vr[i];
        }
        __syncthreads();
        if (kt < 15) {                       // prefetch next tile
            int kk = (kt + 1) << 6;
            #pragma unroll
            for (int i = 0; i < 4; ++i) {
                int r = r0 + 16 * i;
                kr[i] = *reinterpret_cast<const ushort4*>(&Kg[(size_t)(kk + r) * 64 + cc]);
                vr[i] = *reinterpret_cast<const ushort4*>(&Vg[(size_t)r * N_ + kk + cc]);
            }
        }

        // S = Q K^T, P = exp2(S) -> Ps  (K-frags shared across both strips)
        #pragma unroll
        for (int kj = 0; kj < 4; ++kj) {
            bf16x8 bk0 = *reinterpret_cast<bf16x8*>(&Ks[(kj * 16 + l16) * 72 + quad * 8]);
            bf16x8 bk1 = *reinterpret_cast<bf16x8*>(&Ks[(kj * 16 + l16) * 72 + 32 + quad * 8]);
            #pragma unroll
            for (int s = 0; s < 2; ++s) {
                f32x4 sv = (f32x4){0.f, 0.f, 0.f, 0.f};
                sv = __builtin_amdgcn_mfma_f32_16x16x32_bf16(aq[s][0], bk0, sv, 0, 0, 0);
                sv = __builtin_amdgcn_mfma_f32_16x16x32_bf16(aq[s][1], bk1, sv, 0, 0, 0);
                #pragma unroll
                for (int j = 0; j < 4; ++j) {
                    float pv = EXP2(sv[j]);
                    Ps[(qs0 + s * 16 + quad * 4 + j) * 72 + kj * 16 + l16] = f2bf_fast(pv);
                }
            }
        }
        __asm__ volatile("s_waitcnt lgkmcnt(0)" ::: "memory");  // wave-local strip

        bf16x8 ap[2][2];
        #pragma unroll
        for (int s = 0; s < 2; ++s) {
            ap[s][0] = *reinterpret_cast<bf16x8*>(&Ps[(qs0 + s * 16 + l16) * 72 + quad * 8]);
            ap[s][1] = *reinterpret_cast<bf16x8*>(&Ps[(qs0 + s * 16 + l16) * 72 + 32 + quad * 8]);
            lacc[s] = __builtin_amdgcn_mfma_f32_16x16x32_bf16(ap[s][0], ones, lacc[s], 0, 0, 0);
            lacc[s] = __builtin_amdgcn_mfma_f32_16x16x32_bf16(ap[s][1], ones, lacc[s], 0, 0, 0);
        }
        // O += P.V   (V-frags shared across both strips)
        #pragma unroll
        for (int cs = 0; cs < 4; ++cs) {
            bf16x8 bv0 = *reinterpret_cast<bf16x8*>(&Vs[(cs * 16 + l16) * 72 + quad * 8]);
            bf16x8 bv1 = *reinterpret_cast<bf16x8*>(&Vs[(cs * 16 + l16) * 72 + 32 + quad * 8]);
            #pragma unroll
            for (int s = 0; s < 2; ++s) {
                oacc[s][cs] = __builtin_amdgcn_mfma_f32_16x16x32_bf16(ap[s][0], bv0, oacc[s][cs], 0, 0, 0);
                oacc[s][cs] = __builtin_amdgcn_mfma_f32_16x16x32_bf16(ap[s][1], bv1, oacc[s][cs], 0, 0, 0);
            }
        }
    }

    // private bf16 partials: each address written exactly once grid-wide
    unsigned short* Og = Opart + (((size_t)ks * B_ + b) * N_ + q0) * 64;
    #pragma unroll
    for (int s = 0; s < 2; ++s)
        #pragma unroll
        for (int j = 0; j < 4; ++j) {
            int row = qs0 + s * 16 + quad * 4 + j;
            #pragma unroll
            for (int cs = 0; cs < 4; ++cs)
                Og[row * 64 + cs * 16 + l16] = f2bf_fast(oacc[s][cs][j]);
        }
    if (l16 == 0) {
        #pragma unroll
        for (int s = 0; s < 2; ++s)
            #pragma unroll
            for (int j = 0; j < 4; ++j)
                lpart[((size_t)ks * B_ + b) * N_ + q0 + qs0 + s * 16 + quad * 4 + j]
                    = lacc[s][j];
    }
}

// ---------------------------------------------------------------- kernel 3
// MFMA epilogue, channel halves (grid 512): bf16 partials summed coalesced
// into fp32 LDS, float4 x staging, then frags from LDS.
__global__ __launch_bounds__(256) void epi_kernel(
    const unsigned short* __restrict__ Opart, const float* __restrict__ lpart,
    const float* __restrict__ x, const float* __restrict__ gate,
    const float* __restrict__ Wo, const float* __restrict__ bo,
    float* __restrict__ out)
{
    __shared__ float xs[64 * 68];            // [p][c]
    __shared__ float osum[64 * 68];          // [p][c] summed partials
    __shared__ unsigned short Wl[32 * 72];   // [o_local][c] bf16
    __shared__ float os[32 * 68];            // out repack [o_local][p]

    int tid  = threadIdx.x;
    int bx   = blockIdx.x;
    int half = bx >> 8;
    int rem  = bx & 255;
    int b  = rem >> 6;
    int p0 = (rem & 63) << 6;
    const float* xb = x + (size_t)b * (C_ * N_) + p0;

    // stage x [p][c] via float4 loads
    #pragma unroll
    for (int i = 0; i < 4; ++i) {
        int u = tid + i * 256;
        int c = u >> 4, p4 = (u & 15) << 2;
        float4 v = *reinterpret_cast<const float4*>(&xb[(size_t)c * N_ + p4]);
        xs[(p4 + 0) * 68 + c] = v.x;
        xs[(p4 + 1) * 68 + c] = v.y;
        xs[(p4 + 2) * 68 + c] = v.z;
        xs[(p4 + 3) * 68 + c] = v.w;
    }
    {   // sum 4 bf16 ksplit partials, coalesced uint2 (4 bf16 each)
        const unsigned short* Ob = Opart + ((size_t)b * N_ + p0) * 64;
        const size_t kstride = (size_t)B_ * N_ * 64;   // ushorts
        #pragma unroll
        for (int i = 0; i < 4; ++i) {
            int u = tid + i * 256;           // 1024 units of 4 c
            int p = u >> 4, c4 = (u & 15) << 2;
            size_t off = (size_t)p * 64 + c4;
            uint2 a0 = *reinterpret_cast<const uint2*>(&Ob[off]);
            uint2 a1 = *reinterpret_cast<const uint2*>(&Ob[off + kstride]);
            uint2 a2 = *reinterpret_cast<const uint2*>(&Ob[off + 2 * kstride]);
            uint2 a3 = *reinterpret_cast<const uint2*>(&Ob[off + 3 * kstride]);
            float4 ssum;
            ssum.x = (bflo(a0.x) + bflo(a1.x)) + (bflo(a2.x) + bflo(a3.x));
            ssum.y = (bfhi(a0.x) + bfhi(a1.x)) + (bfhi(a2.x) + bfhi(a3.x));
            ssum.z = (bflo(a0.y) + bflo(a1.y)) + (bflo(a2.y) + bflo(a3.y));
            ssum.w = (bfhi(a0.y) + bfhi(a1.y)) + (bfhi(a2.y) + bfhi(a3.y));
            *reinterpret_cast<float4*>(&osum[p * 68 + c4]) = ssum;
        }
    }
    {   // Wo rows half*32..+31 -> bf16 LDS
        int ol = tid >> 3;
        int cb = (tid & 7) << 3;
        const float4* src = reinterpret_cast<const float4*>(
            &Wo[(half * 32 + ol) * 64 + cb]);
        float4 w0 = src[0], w1 = src[1];
        uint2 pkd;
        pkd.x = pack2bf(w0.x, w0.y); pkd.y = pack2bf(w0.z, w0.w);
        *reinterpret_cast<uint2*>(&Wl[ol * 72 + cb]) = pkd;
        pkd.x = pack2bf(w1.x, w1.y); pkd.y = pack2bf(w1.z, w1.w);
        *reinterpret_cast<uint2*>(&Wl[ol * 72 + cb + 4]) = pkd;
    }
    __syncthreads();

    int lane = tid & 63;
    int wv   = __builtin_amdgcn_readfirstlane(tid >> 6);
    int quad = lane >> 4, l16 = lane & 15;
    int prow = wv * 16 + l16;
    int pos  = p0 + prow;

    float lv = lpart[(size_t)b * N_ + pos]
             + lpart[((size_t)B_ + b) * N_ + pos]
             + lpart[(2 * (size_t)B_ + b) * N_ + pos]
             + lpart[(3 * (size_t)B_ + b) * N_ + pos];
    float gi = gate[b * N_ + pos] / lv;

    bf16x8 bt[2];
    #pragma unroll
    for (int chunk = 0; chunk < 2; ++chunk) {
        int cb2 = chunk * 32 + quad * 8;
        float4 oa = *reinterpret_cast<float4*>(&osum[prow * 68 + cb2]);
        float4 ob4 = *reinterpret_cast<float4*>(&osum[prow * 68 + cb2 + 4]);
        float4 xa = *reinterpret_cast<float4*>(&xs[prow * 68 + cb2]);
        float4 xb4 = *reinterpret_cast<float4*>(&xs[prow * 68 + cb2 + 4]);
        bt[chunk][0] = f2bf(fmaf(oa.x, gi, xa.x));
        bt[chunk][1] = f2bf(fmaf(oa.y, gi, xa.y));
        bt[chunk][2] = f2bf(fmaf(oa.z, gi, xa.z));
        bt[chunk][3] = f2bf(fmaf(oa.w, gi, xa.w));
        bt[chunk][4] = f2bf(fmaf(ob4.x, gi, xb4.x));
        bt[chunk][5] = f2bf(fmaf(ob4.y, gi, xb4.y));
        bt[chunk][6] = f2bf(fmaf(ob4.z, gi, xb4.z));
        bt[chunk][7] = f2bf(fmaf(ob4.w, gi, xb4.w));
    }

    #pragma unroll
    for (int tt = 0; tt < 2; ++tt) {
        int ot = half * 2 + tt;
        bf16x8 a0 = *reinterpret_cast<bf16x8*>(&Wl[(tt * 16 + l16) * 72 + quad * 8]);
        bf16x8 a1 = *reinterpret_cast<bf16x8*>(&Wl[(tt * 16 + l16) * 72 + 32 + quad * 8]);
        f32x4 c4 = (f32x4){0.f, 0.f, 0.f, 0.f};
        c4 = __builtin_amdgcn_mfma_f32_16x16x32_bf16(a0, bt[0], c4, 0, 0, 0);
        c4 = __builtin_amdgcn_mfma_f32_16x16x32_bf16(a1, bt[1], c4, 0, 0, 0);
        float4 bias = *reinterpret_cast<const float4*>(&bo[ot * 16 + quad * 4]);
        c4[0] += bias.x; c4[1] += bias.y; c4[2] += bias.z; c4[3] += bias.w;
        #pragma unroll
        for (int j = 0; j < 4; ++j)
            os[(tt * 16 + quad * 4 + j) * 68 + prow] = c4[j];
    }
    __syncthreads();

    int row = tid >> 3;
    int pb  = (tid & 7) << 3;
    float* ob = out + ((size_t)b * 64 + half * 32 + row) * N_ + p0 + pb;
    *reinterpret_cast<float4*>(ob)     = *reinterpret_cast<float4*>(&os[row * 68 + pb]);
    *reinterpret_cast<float4*>(ob + 4) = *reinterpret_cast<float4*>(&os[row * 68 + pb + 4]);
}

// ---------------------------------------------------------------- launch
extern "C" void kernel_launch(void* const* d_in, const int* in_sizes, int n_in,
                              void* d_out, int out_size, void* d_ws, size_t ws_size,
                              hipStream_t stream)
{
    const float* x   = (const float*)d_in[0];
    const float* fp  = (const float*)d_in[1];
    const float* Wq  = (const float*)d_in[2];
    const float* bq  = (const float*)d_in[3];
    const float* Wk  = (const float*)d_in[4];
    const float* bk  = (const float*)d_in[5];
    const float* Wv  = (const float*)d_in[6];
    const float* bv  = (const float*)d_in[7];
    const float* Wo  = (const float*)d_in[8];
    const float* bo  = (const float*)d_in[9];
    const float* Wfp = (const float*)d_in[10];
    const float* bfp = (const float*)d_in[11];
    float* out = (float*)d_out;

    char* ws = (char*)d_ws;
    float* gate = (float*)(ws);                                      // 64 KB
    unsigned short* Qb = (unsigned short*)(ws + 65536);              // 2 MB
    unsigned short* Kb = (unsigned short*)(ws + 65536 + 2097152);    // 2 MB
    unsigned short* Vb = (unsigned short*)(ws + 65536 + 2 * 2097152);// 2 MB
    unsigned short* Opart = (unsigned short*)(ws + 65536 + 3 * 2097152); // 8 MB bf16
    float* lpart = (float*)(ws + 65536 + 3 * 2097152 + 8388608);     // 256 KB

    // no memset needed: every Opart/lpart element is written exactly once

    hipLaunchKernelGGL(qkv_kernel, dim3(768), dim3(256), 0, stream,
                       x, Wq, bq, Wk, bk, Wv, bv, fp, Wfp, bfp,
                       gate, Qb, Kb, Vb);
    hipLaunchKernelGGL(attn_kernel, dim3(512), dim3(256), 0, stream,
                       Qb, Kb, Vb, Opart, lpart);
    hipLaunchKernelGGL(epi_kernel, dim3(512), dim3(256), 0, stream,
                       Opart, lpart, x, gate, Wo, bo, out);
}